// Round 3
// baseline (70.366 us; speedup 1.0000x reference)
//
#include <hip/hip_runtime.h>

#define N_LATENT 128
#define N_OUT    128
#define CAPS     256   // slist capacity (mean per block 16.4; never approached)
#define CAPU     64    // u rows staged in LDS (32 KB); overflow has a slow path

__global__ __launch_bounds__(128, 1) void ldz_kernel(
    const float* __restrict__ u,
    const int*   __restrict__ donor_id,
    const float* __restrict__ amat,
    const float* __restrict__ offsets,
    float*       __restrict__ out,
    int B)
{
    const int d   = blockIdx.x >> 1;   // 2 blocks per donor (sample-parity split)
    const int par = blockIdx.x & 1;
    const int t   = threadIdx.x;       // output column o, 0..127

    __shared__ int   slist[CAPS];
    __shared__ int   scount;
    __shared__ float us[CAPU][N_LATENT];   // staged u rows, 32 KB

    if (t == 0) scount = 0;
    __syncthreads();

    // ---- Issue A-column loads first (latency overlaps the scan) ----
    float a[N_LATENT];
    const float* ab = amat + (size_t)d * N_LATENT * N_OUT + t;
    #pragma unroll
    for (int l = 0; l < N_LATENT; ++l) a[l] = ab[(size_t)l * N_OUT];

    // ---- Scan donor ids (int4), compact parity-matching sample indices ----
    const int4* did4 = (const int4*)donor_id;
    const int nq = B >> 2;
    #pragma unroll 4
    for (int i = t; i < nq; i += 128) {
        int4 v = did4[i];
        int b = 4 * i;
        if (v.x == d && ((b + 0) & 1) == par) { int p = atomicAdd(&scount, 1); if (p < CAPS) slist[p] = b + 0; }
        if (v.y == d && ((b + 1) & 1) == par) { int p = atomicAdd(&scount, 1); if (p < CAPS) slist[p] = b + 1; }
        if (v.z == d && ((b + 2) & 1) == par) { int p = atomicAdd(&scount, 1); if (p < CAPS) slist[p] = b + 2; }
        if (v.w == d && ((b + 3) & 1) == par) { int p = atomicAdd(&scount, 1); if (p < CAPS) slist[p] = b + 3; }
    }
    __syncthreads();
    const int n      = min(scount, CAPS);
    const int nstage = min(n, CAPU);

    // ---- Stage this block's u rows into LDS (coalesced float4) ----
    // thread t covers row r0+(t>>5), float4 column t&31 (4 rows per pass)
    for (int r0 = 0; r0 < nstage; r0 += 4) {
        int r = r0 + (t >> 5);
        if (r < nstage) {
            int b = slist[r];
            ((float4*)us[r])[t & 31] = ((const float4*)(u + (size_t)b * N_LATENT))[t & 31];
        }
    }

    // ---- Pin A in arch VGPRs (R2 bug: allocator spilled it at VGPR=72).
    // launch_bounds(128,1) gives a 512-reg budget so ~170 live fits. ----
    #pragma unroll
    for (int l = 0; l < N_LATENT; ++l) asm volatile("" : "+v"(a[l]));

    const float off = offsets[(size_t)d * N_OUT + t];
    __syncthreads();

    // ---- Main loop: 2 samples per iteration, u via LDS broadcast float4 ----
    int s = 0;
    for (; s + 1 < nstage; s += 2) {
        const int b0 = slist[s], b1 = slist[s + 1];
        float p0 = 0.f, q0 = 0.f, p1 = 0.f, q1 = 0.f;
        #pragma unroll
        for (int l = 0; l < N_LATENT; l += 4) {
            float4 u0 = *(const float4*)&us[s][l];       // broadcast read
            float4 u1 = *(const float4*)&us[s + 1][l];
            p0 = fmaf(u0.x, a[l],     p0);  q0 = fmaf(u0.y, a[l + 1], q0);
            p0 = fmaf(u0.z, a[l + 2], p0);  q0 = fmaf(u0.w, a[l + 3], q0);
            p1 = fmaf(u1.x, a[l],     p1);  q1 = fmaf(u1.y, a[l + 1], q1);
            p1 = fmaf(u1.z, a[l + 2], p1);  q1 = fmaf(u1.w, a[l + 3], q1);
        }
        out[(size_t)b0 * N_OUT + t] = us[s][t]     + off + p0 + q0;
        out[(size_t)b1 * N_OUT + t] = us[s + 1][t] + off + p1 + q1;
    }
    if (s < nstage) {   // odd tail
        const int b0 = slist[s];
        float p0 = 0.f, q0 = 0.f;
        #pragma unroll
        for (int l = 0; l < N_LATENT; l += 4) {
            float4 u0 = *(const float4*)&us[s][l];
            p0 = fmaf(u0.x, a[l],     p0);  q0 = fmaf(u0.y, a[l + 1], q0);
            p0 = fmaf(u0.z, a[l + 2], p0);  q0 = fmaf(u0.w, a[l + 3], q0);
        }
        out[(size_t)b0 * N_OUT + t] = us[s][t] + off + p0 + q0;
    }

    // ---- Overflow stragglers (statistically never; correctness only) ----
    for (int s2 = nstage; s2 < n; ++s2) {
        const int b = slist[s2];
        const float* ub = u + (size_t)b * N_LATENT;
        float acc = 0.f;
        #pragma unroll
        for (int l = 0; l < N_LATENT; ++l) acc = fmaf(ub[l], a[l], acc);
        out[(size_t)b * N_OUT + t] = ub[t] + off + acc;
    }
}

extern "C" void kernel_launch(void* const* d_in, const int* in_sizes, int n_in,
                              void* d_out, int out_size, void* d_ws, size_t ws_size,
                              hipStream_t stream) {
    const float* u        = (const float*)d_in[0];
    const int*   donor_id = (const int*)d_in[1];
    const float* amat     = (const float*)d_in[2];
    const float* offsets  = (const float*)d_in[3];
    float*       out      = (float*)d_out;

    const int B        = in_sizes[1];           // 16384
    const int n_donors = in_sizes[3] / N_OUT;   // 500

    hipLaunchKernelGGL(ldz_kernel, dim3(n_donors * 2), dim3(128), 0, stream,
                       u, donor_id, amat, offsets, out, B);
}

// Round 4
// 40.199 us; speedup vs baseline: 1.7505x; 1.7505x over previous
//
#include <hip/hip_runtime.h>

#define N_LATENT 128
#define N_OUT    128
#define NB       2      // parity blocks (and bins) per donor
#define BIN_CAP  128    // per-(donor,parity) bin capacity; mean 16.4, P(>128)~1e-50
#define CHUNK    32     // u rows staged per LDS pass (16 KB)

// ---- K1: bin sample indices by (donor, parity) into d_ws ----
__global__ void bin_kernel(const int* __restrict__ donor_id,
                           int* __restrict__ cnt, int* __restrict__ bins, int B)
{
    int b = blockIdx.x * blockDim.x + threadIdx.x;
    if (b >= B) return;
    int bin = donor_id[b] * NB + (b & (NB - 1));
    int pos = atomicAdd(&cnt[bin], 1);
    if (pos < BIN_CAP) bins[bin * BIN_CAP + pos] = b;
}

// ---- K2: per-donor matvec. Thread (h,o) holds A[d][h*64+i][o] (64 VGPRs);
// h-partner is lane^32 in the SAME wave -> shfl reduction, no barriers.  ----
__global__ __launch_bounds__(256, 4) void matvec_kernel(
    const float* __restrict__ u,
    const float* __restrict__ amat,
    const float* __restrict__ offsets,
    const int*   __restrict__ cnt,
    const int*   __restrict__ bins,
    float*       __restrict__ out)
{
    const int bin = blockIdx.x;
    const int d   = bin >> 1;
    const int t   = threadIdx.x;
    const int h   = (t >> 5) & 1;                  // latent half, partner = lane^32
    const int o   = (t & 31) | ((t >> 6) << 5);    // output column

    __shared__ float us[CHUNK][N_LATENT];
    __shared__ int   slist[BIN_CAP];

    // Issue A loads first; latency overlaps slist/offsets loads.
    float a[64];
    const float* ab = amat + ((size_t)d * N_LATENT + h * 64) * N_OUT + o;
    #pragma unroll
    for (int i = 0; i < 64; ++i) a[i] = ab[(size_t)i * N_OUT];

    const int n = min(cnt[bin], BIN_CAP);
    for (int i = t; i < n; i += 256) slist[i] = bins[bin * BIN_CAP + i];

    const float off = offsets[(size_t)d * N_OUT + o];

    // Pin A in arch VGPRs (R1/R2: compiler remat/spilled it; R3: resident but
    // at 244 regs it strangled pipelining — here 64+overhead ≈ ~110 regs).
    #pragma unroll
    for (int i = 0; i < 64; ++i) asm volatile("" : "+v"(a[i]));

    __syncthreads();

    for (int c0 = 0; c0 < n; c0 += CHUNK) {
        const int m = min(CHUNK, n - c0);
        // stage u rows for this chunk (coalesced float4; 8 rows per pass)
        for (int r = t >> 5; r < m; r += 8) {
            int b = slist[c0 + r];
            ((float4*)us[r])[t & 31] = ((const float4*)(u + (size_t)b * N_LATENT))[t & 31];
        }
        __syncthreads();

        int s = 0;
        for (; s + 1 < m; s += 2) {
            const int b0 = __builtin_amdgcn_readfirstlane(slist[c0 + s]);
            const int b1 = __builtin_amdgcn_readfirstlane(slist[c0 + s + 1]);
            const float* u0 = &us[s][h * 64];       // 2-addr broadcast (free 2-way)
            const float* u1 = &us[s + 1][h * 64];
            float p0 = 0.f, q0 = 0.f, p1 = 0.f, q1 = 0.f;
            #pragma unroll
            for (int i = 0; i < 64; i += 4) {
                float4 x0 = *(const float4*)(u0 + i);
                float4 x1 = *(const float4*)(u1 + i);
                p0 = fmaf(x0.x, a[i],     p0);  q0 = fmaf(x0.y, a[i + 1], q0);
                p0 = fmaf(x0.z, a[i + 2], p0);  q0 = fmaf(x0.w, a[i + 3], q0);
                p1 = fmaf(x1.x, a[i],     p1);  q1 = fmaf(x1.y, a[i + 1], q1);
                p1 = fmaf(x1.z, a[i + 2], p1);  q1 = fmaf(x1.w, a[i + 3], q1);
            }
            float r0 = p0 + q0;  r0 += __shfl_xor(r0, 32);
            float r1 = p1 + q1;  r1 += __shfl_xor(r1, 32);
            if (h == 0) {
                out[(size_t)b0 * N_OUT + o] = us[s][o]     + off + r0;
                out[(size_t)b1 * N_OUT + o] = us[s + 1][o] + off + r1;
            }
        }
        if (s < m) {
            const int b0 = __builtin_amdgcn_readfirstlane(slist[c0 + s]);
            const float* u0 = &us[s][h * 64];
            float p0 = 0.f, q0 = 0.f;
            #pragma unroll
            for (int i = 0; i < 64; i += 4) {
                float4 x0 = *(const float4*)(u0 + i);
                p0 = fmaf(x0.x, a[i],     p0);  q0 = fmaf(x0.y, a[i + 1], q0);
                p0 = fmaf(x0.z, a[i + 2], p0);  q0 = fmaf(x0.w, a[i + 3], q0);
            }
            float r0 = p0 + q0;  r0 += __shfl_xor(r0, 32);
            if (h == 0)
                out[(size_t)b0 * N_OUT + o] = us[s][o] + off + r0;
        }
        __syncthreads();   // us reused next chunk (no-op cost when single chunk)
    }
}

extern "C" void kernel_launch(void* const* d_in, const int* in_sizes, int n_in,
                              void* d_out, int out_size, void* d_ws, size_t ws_size,
                              hipStream_t stream) {
    const float* u        = (const float*)d_in[0];
    const int*   donor_id = (const int*)d_in[1];
    const float* amat     = (const float*)d_in[2];
    const float* offsets  = (const float*)d_in[3];
    float*       out      = (float*)d_out;

    const int B        = in_sizes[1];           // 16384
    const int n_donors = in_sizes[3] / N_OUT;   // 500
    const int n_bins   = n_donors * NB;

    // ws layout: [0, n_bins*4) counts | [4096, 4096 + n_bins*BIN_CAP*4) bins
    int* cnt  = (int*)d_ws;
    int* bins = (int*)((char*)d_ws + 4096);
    // (needs 4096 + 1000*128*4 = 516 KB of ws)

    hipMemsetAsync(cnt, 0, (size_t)n_bins * sizeof(int), stream);
    hipLaunchKernelGGL(bin_kernel, dim3((B + 255) / 256), dim3(256), 0, stream,
                       donor_id, cnt, bins, B);
    hipLaunchKernelGGL(matvec_kernel, dim3(n_bins), dim3(256), 0, stream,
                       u, amat, offsets, cnt, bins, out);
}